// Round 1
// baseline (262.645 us; speedup 1.0000x reference)
//
#include <hip/hip_runtime.h>
#include <hip/hip_bf16.h>
#include <stdint.h>

// ---------------------------------------------------------------------------
// PiCO forward: B=4096, D_IN=1024, LOW_DIM=128, NUM_CLASS=32, MOCO_QUEUE=65536
// ---------------------------------------------------------------------------

typedef __attribute__((ext_vector_type(8))) short bf16x8;
typedef __attribute__((ext_vector_type(4))) float f32x4;

// output offsets (in floats), concatenated in reference return order
constexpr size_t O0 = 0;          // output            (4096,32)
constexpr size_t O1 = 131072;     // features          (73728,128)
constexpr size_t O2 = 9568256;    // pseudo_scores     (73728,32)
constexpr size_t O3 = 11927552;   // partial_target    (73728,32)
constexpr size_t O4 = 14286848;   // score_prot        (4096,32)
constexpr size_t O5 = 14417920;   // new_protos        (32,128)
constexpr size_t O6 = 14422016;   // new_queue         (65536,128)
constexpr size_t O7 = 22810624;   // new_queue_pseudo  (65536,32)
constexpr size_t O8 = 24907776;   // new_queue_partial (65536,32)

__device__ __forceinline__ unsigned short f2b(float x) {
  union { float f; uint32_t u; } v; v.f = x;
  uint32_t u = v.u;
  uint32_t r = (u + 0x7fffu + ((u >> 16) & 1u)) >> 16;   // RNE f32->bf16
  return (unsigned short)r;
}

// ---------------------------------------------------------------------------
// prep_w: Wt[n][k] = bf16(a1*W1[k][n] + a2*W2[k][n]); W is [1024][N] f32.
// grid (1024/32, N/32), block (32,8). LDS-tiled transpose.
// ---------------------------------------------------------------------------
__global__ __launch_bounds__(256) void prep_w(const float* __restrict__ W1,
                                              const float* __restrict__ W2,
                                              float a1, float a2, int N,
                                              unsigned short* __restrict__ Wt) {
  __shared__ float tile[32][33];
  const int kb = blockIdx.x * 32, nb = blockIdx.y * 32;
  const int tx = threadIdx.x, ty = threadIdx.y;
#pragma unroll
  for (int j = 0; j < 4; ++j) {
    const int k = kb + ty + 8 * j;
    float v = W1[(size_t)k * N + nb + tx] * a1;
    if (W2) v += W2[(size_t)k * N + nb + tx] * a2;
    tile[ty + 8 * j][tx] = v;
  }
  __syncthreads();
#pragma unroll
  for (int j = 0; j < 4; ++j) {
    const int n = nb + ty + 8 * j;
    Wt[(size_t)n * 1024 + kb + tx] = f2b(tile[tx][ty + 8 * j]);
  }
}

// ---------------------------------------------------------------------------
// gemm_enc<NWAVES>: C[M=4096][BN] = A[4096][1024] @ Wt^T, Wt is bf16 [BN][1024].
// BM=16, BK=64, one 32-col strip per wave. mfma_f32_16x16x32_bf16.
// A staged f32->bf16 (reg), both LDS tiles XOR-swizzled (byte ^= (row&7)<<4).
// grid = 256 blocks (M/16), block = NWAVES*64.
// ---------------------------------------------------------------------------
template <int NWAVES>
__global__ __launch_bounds__(NWAVES * 64) void gemm_enc(
    const float* __restrict__ A, const unsigned short* __restrict__ Wt,
    float* __restrict__ C) {
  constexpr int BN = NWAVES * 32;
  constexpr int NT = NWAVES * 64;
  constexpr int K = 1024;
  __shared__ __align__(16) unsigned char sA[16 * 128];
  __shared__ __align__(16) unsigned char sB[BN * 128];
  const int t = threadIdx.x;
  const int w = t >> 6, l = t & 63;
  const int ar = l & 15, kg = l >> 4;
  const int cs = w * 32;
  const int m0 = blockIdx.x * 16;
  f32x4 acc0 = {0.f, 0.f, 0.f, 0.f}, acc1 = {0.f, 0.f, 0.f, 0.f};
  for (int k0 = 0; k0 < K; k0 += 64) {
    if (t < 256) {
      const int r = t >> 4;
      const int c8 = (t & 15) * 8;  // byte offset within 128B row
      const float4 v = *(const float4*)(A + (size_t)(m0 + r) * K + k0 + (t & 15) * 4);
      uint2 pk;
      pk.x = (uint32_t)f2b(v.x) | ((uint32_t)f2b(v.y) << 16);
      pk.y = (uint32_t)f2b(v.z) | ((uint32_t)f2b(v.w) << 16);
      *(uint2*)(sA + ((r * 128 + c8) ^ ((r & 7) << 4))) = pk;
    }
#pragma unroll
    for (int i = 0; i < (BN * 8) / NT; ++i) {
      const int cid = t + i * NT;
      const int r = cid >> 3, c = cid & 7;
      const uint4 v = *(const uint4*)(Wt + (size_t)r * K + k0 + c * 8);
      *(uint4*)(sB + ((r * 128 + c * 16) ^ ((r & 7) << 4))) = v;
    }
    __syncthreads();
#pragma unroll
    for (int s = 0; s < 2; ++s) {
      const int ch = (s * 4 + kg) * 16;
      bf16x8 a = *(const bf16x8*)(sA + ((ar * 128 + ch) ^ ((ar & 7) << 4)));
      const int r0 = cs + ar, r1 = cs + 16 + ar;
      bf16x8 b0 = *(const bf16x8*)(sB + ((r0 * 128 + ch) ^ ((r0 & 7) << 4)));
      bf16x8 b1 = *(const bf16x8*)(sB + ((r1 * 128 + ch) ^ ((r1 & 7) << 4)));
      acc0 = __builtin_amdgcn_mfma_f32_16x16x32_bf16(a, b0, acc0, 0, 0, 0);
      acc1 = __builtin_amdgcn_mfma_f32_16x16x32_bf16(a, b1, acc1, 0, 0, 0);
    }
    __syncthreads();
  }
#pragma unroll
  for (int j = 0; j < 4; ++j) {
    const int row = m0 + kg * 4 + j;
    C[(size_t)row * BN + cs + ar] = acc0[j];
    C[(size_t)row * BN + cs + 16 + ar] = acc1[j];
  }
}

// ---------------------------------------------------------------------------
// post_q: per-row epilogue for the query encoder.
// CQ row layout: [0:128) = raw proj, [128:160) = raw logits.
// Computes: output(+bias), softmax*partial_Y (3 dests), partial_Y (3 dests),
// argmax->labels, l2norm(q)->features, score_prot=softmax(q@protoT).
// grid 1024, block 256 (wave w handles row blk*4+w).
// ---------------------------------------------------------------------------
__global__ __launch_bounds__(256) void post_q(
    const float* __restrict__ CQ, const float* __restrict__ bias,
    const float* __restrict__ partialY, const float* __restrict__ protos,
    float* __restrict__ out, int* __restrict__ labels) {
  __shared__ float pr[32 * 129];  // padded: bank = (c + d) % 32, conflict-free
  __shared__ float qs[4][128];
  const int t = threadIdx.x;
  for (int i = t; i < 4096; i += 256) pr[(i >> 7) * 129 + (i & 127)] = protos[i];
  __syncthreads();
  const int w = t >> 6, l = t & 63;
  const int row = blockIdx.x * 4 + w;
  const float* cq = CQ + (size_t)row * 160;

  // logits + bias, softmax, * partial_Y
  float logit = -1e30f;
  if (l < 32) logit = cq[128 + l] + bias[l];
  float m = logit;
  for (int o = 32; o; o >>= 1) m = fmaxf(m, __shfl_xor(m, o));
  const float e = (l < 32) ? __expf(logit - m) : 0.f;
  float ssum = e;
  for (int o = 32; o; o >>= 1) ssum += __shfl_xor(ssum, o);
  const float py = (l < 32) ? partialY[(size_t)row * 32 + l] : 0.f;
  const float p = e / ssum * py;
  if (l < 32) {
    out[O0 + (size_t)row * 32 + l] = logit;
    out[O2 + (size_t)row * 32 + l] = p;
    out[O2 + (size_t)(4096 + row) * 32 + l] = p;
    out[O7 + (size_t)row * 32 + l] = p;
    out[O3 + (size_t)row * 32 + l] = py;
    out[O3 + (size_t)(4096 + row) * 32 + l] = py;
    out[O8 + (size_t)row * 32 + l] = py;
  }
  // argmax (first-index-wins on ties, matches jnp.argmax)
  float av = (l < 32) ? p : -1.f;
  int ai = (l < 32) ? l : 1000;
  for (int o = 32; o; o >>= 1) {
    const float ov = __shfl_xor(av, o);
    const int oi = __shfl_xor(ai, o);
    if (ov > av || (ov == av && oi < ai)) { av = ov; ai = oi; }
  }
  if (l == 0) labels[row] = ai;

  // l2norm(q)
  float v0 = cq[l], v1 = cq[64 + l];
  float ss = v0 * v0 + v1 * v1;
  for (int o = 32; o; o >>= 1) ss += __shfl_xor(ss, o);
  const float den = fmaxf(sqrtf(ss), 1e-12f);
  v0 /= den; v1 /= den;
  out[O1 + (size_t)row * 128 + l] = v0;
  out[O1 + (size_t)row * 128 + 64 + l] = v1;
  qs[w][l] = v0;
  qs[w][64 + l] = v1;   // same-wave LDS: lockstep, no barrier needed

  // score_prot: lane pair (l, l+32) splits the 128-dim dot for class c=l&31
  const int c = l & 31;
  const int dh = (l >> 5) * 64;
  float acc = 0.f;
#pragma unroll
  for (int d = 0; d < 64; ++d) acc += qs[w][dh + d] * pr[c * 129 + dh + d];
  acc += __shfl_xor(acc, 32);
  float sm = acc;
  for (int o = 16; o; o >>= 1) sm = fmaxf(sm, __shfl_xor(sm, o));
  const float ee = __expf(acc - sm);
  float s2 = ee;
  for (int o = 16; o; o >>= 1) s2 += __shfl_xor(s2, o);
  if (l < 32) out[O4 + (size_t)row * 32 + l] = ee / s2;
}

// ---------------------------------------------------------------------------
// post_k: kfeat = l2norm(CK row) -> features[B+i], new_queue[i]
// ---------------------------------------------------------------------------
__global__ __launch_bounds__(256) void post_k(const float* __restrict__ CK,
                                              float* __restrict__ out) {
  const int t = threadIdx.x, w = t >> 6, l = t & 63;
  const int row = blockIdx.x * 4 + w;
  const float* ck = CK + (size_t)row * 128;
  float v0 = ck[l], v1 = ck[64 + l];
  float ss = v0 * v0 + v1 * v1;
  for (int o = 32; o; o >>= 1) ss += __shfl_xor(ss, o);
  const float den = fmaxf(sqrtf(ss), 1e-12f);
  v0 /= den; v1 /= den;
  out[O1 + (size_t)(4096 + row) * 128 + l] = v0;
  out[O1 + (size_t)(4096 + row) * 128 + 64 + l] = v1;
  out[O6 + (size_t)row * 128 + l] = v0;
  out[O6 + (size_t)row * 128 + 64 + l] = v1;
}

// ---------------------------------------------------------------------------
// proto_up: order-dependent per-class EMA scan, parallelized as weighted sum.
// new_p[c] = p[c]*m^k + sum_j (1-m)*m^(k-1-j)*q[list_j], then row l2norm.
// One block per class (32), 128 threads (one per dim).
// ---------------------------------------------------------------------------
__global__ __launch_bounds__(128) void proto_up(const int* __restrict__ labels,
                                                const float* __restrict__ qfeat,
                                                const float* __restrict__ protos,
                                                float* __restrict__ out) {
  __shared__ int lab[4096];   // reused as float weights after list build
  __shared__ int list[4096];
  __shared__ int cnt[128];
  __shared__ int ktot;
  __shared__ float red[2];
  const int c = blockIdx.x, t = threadIdx.x;
  for (int i = t; i < 4096; i += 128) lab[i] = labels[i];
  __syncthreads();
  int cn = 0;
#pragma unroll
  for (int j = 0; j < 32; ++j) {
    const int jj = (j + t) & 31;  // staggered to dodge bank conflicts
    cn += (lab[t * 32 + jj] == c) ? 1 : 0;
  }
  cnt[t] = cn;
  __syncthreads();
  if (t == 0) {
    int s = 0;
    for (int i = 0; i < 128; ++i) { const int v = cnt[i]; cnt[i] = s; s += v; }
    ktot = s;
  }
  __syncthreads();
  int off = cnt[t];
  for (int j = 0; j < 32; ++j) {       // in-order append (order matters)
    const int i = t * 32 + j;
    if (lab[i] == c) list[off++] = i;
  }
  __syncthreads();
  const int k = ktot;
  float* wf = (float*)lab;             // lab dead from here on
  for (int j = t; j < k; j += 128)
    wf[j] = 0.01f * __powf(0.99f, (float)(k - 1 - j));
  __syncthreads();
  float acc = protos[(size_t)c * 128 + t] * __powf(0.99f, (float)k);
  for (int j = 0; j < k; ++j)
    acc += wf[j] * qfeat[(size_t)list[j] * 128 + t];
  float ss = acc * acc;
  for (int o = 32; o; o >>= 1) ss += __shfl_xor(ss, o);
  if ((t & 63) == 0) red[t >> 6] = ss;
  __syncthreads();
  const float tot = red[0] + red[1];
  out[O5 + (size_t)c * 128 + t] = acc / fmaxf(sqrtf(tot), 1e-12f);
}

// ---------------------------------------------------------------------------
// copy_bufs: queue -> features[2B:], new_queue[B:]; queue_pseudo ->
// pseudo_scores[2B:], new_queue_pseudo[B:]; queue_partial analogously.
// float4 grid-stride; each source element read once, written 1-2x.
// ---------------------------------------------------------------------------
__global__ __launch_bounds__(256) void copy_bufs(const float* __restrict__ queue,
                                                 const float* __restrict__ qp,
                                                 const float* __restrict__ qpt,
                                                 float* __restrict__ out) {
  constexpr long NQ4 = (long)65536 * 128 / 4;  // 2097152
  constexpr long NP4 = (long)65536 * 32 / 4;   // 524288
  constexpr long TOT = NQ4 + 2 * NP4;
  float4* o4 = (float4*)out;
  for (long idx = (long)blockIdx.x * blockDim.x + threadIdx.x; idx < TOT;
       idx += (long)gridDim.x * blockDim.x) {
    if (idx < NQ4) {
      const float4 v = ((const float4*)queue)[idx];
      o4[O1 / 4 + (2L * 4096 * 128) / 4 + idx] = v;             // features sec 2
      if ((idx >> 5) >= 4096) o4[O6 / 4 + idx] = v;             // new_queue rows >= B
    } else if (idx < NQ4 + NP4) {
      const long i = idx - NQ4;
      const float4 v = ((const float4*)qp)[i];
      o4[O2 / 4 + (2L * 4096 * 32) / 4 + i] = v;                // pseudo_scores sec 2
      if ((i >> 3) >= 4096) o4[O7 / 4 + i] = v;                 // new_queue_pseudo
    } else {
      const long i = idx - NQ4 - NP4;
      const float4 v = ((const float4*)qpt)[i];
      o4[O3 / 4 + (2L * 4096 * 32) / 4 + i] = v;                // partial_target sec 2
      if ((i >> 3) >= 4096) o4[O8 / 4 + i] = v;                 // new_queue_partial
    }
  }
}

// ---------------------------------------------------------------------------
extern "C" void kernel_launch(void* const* d_in, const int* in_sizes, int n_in,
                              void* d_out, int out_size, void* d_ws, size_t ws_size,
                              hipStream_t stream) {
  const float* img_q    = (const float*)d_in[0];
  const float* im_k     = (const float*)d_in[1];
  const float* partialY = (const float*)d_in[2];
  const float* W_cls_q  = (const float*)d_in[3];
  const float* b_cls_q  = (const float*)d_in[4];
  const float* W_proj_q = (const float*)d_in[5];
  // d_in[6]=W_cls_k, d_in[7]=b_cls_k: dead (key logits are discarded)
  const float* W_proj_k = (const float*)d_in[8];
  const float* protos   = (const float*)d_in[9];
  const float* queue    = (const float*)d_in[10];
  const float* queue_ps = (const float*)d_in[11];
  const float* queue_pt = (const float*)d_in[12];
  float* out = (float*)d_out;

  // workspace layout (~5.2 MB)
  unsigned short* wtq = (unsigned short*)d_ws;          // bf16 [160][1024]: proj_q^T rows 0..127, cls_q^T rows 128..159
  unsigned short* wtk = wtq + 160 * 1024;               // bf16 [128][1024]: (0.999*Wpk + 0.001*Wpq)^T
  float* CQ = (float*)(wtk + 128 * 1024);               // f32 [4096][160]
  float* CK = CQ + (size_t)4096 * 160;                  // f32 [4096][128]
  int* labels = (int*)(CK + (size_t)4096 * 128);        // int [4096]

  prep_w<<<dim3(32, 4), dim3(32, 8), 0, stream>>>(W_proj_q, nullptr, 1.0f, 0.0f, 128, wtq);
  prep_w<<<dim3(32, 1), dim3(32, 8), 0, stream>>>(W_cls_q, nullptr, 1.0f, 0.0f, 32, wtq + 128 * 1024);
  prep_w<<<dim3(32, 4), dim3(32, 8), 0, stream>>>(W_proj_k, W_proj_q, 0.999f, 0.001f, 128, wtk);
  gemm_enc<5><<<256, 320, 0, stream>>>(img_q, wtq, CQ);
  gemm_enc<4><<<256, 256, 0, stream>>>(im_k, wtk, CK);
  post_q<<<1024, 256, 0, stream>>>(CQ, b_cls_q, partialY, protos, out, labels);
  post_k<<<1024, 256, 0, stream>>>(CK, out);
  proto_up<<<32, 128, 0, stream>>>(labels, out + O1, protos, out);
  copy_bufs<<<2048, 256, 0, stream>>>(queue, queue_ps, queue_pt, out);
}

// Round 2
// 251.950 us; speedup vs baseline: 1.0424x; 1.0424x over previous
//
#include <hip/hip_runtime.h>
#include <hip/hip_bf16.h>
#include <stdint.h>

// ---------------------------------------------------------------------------
// PiCO forward: B=4096, D_IN=1024, LOW_DIM=128, NUM_CLASS=32, MOCO_QUEUE=65536
// Round 2: 4 launches (was 9), split-K=2 atomic GEMM w/ reg prefetch,
// parallel-scan proto_up, copies fused into the epilogue kernel.
// ---------------------------------------------------------------------------

typedef __attribute__((ext_vector_type(8))) short bf16x8;
typedef __attribute__((ext_vector_type(4))) float f32x4;

// output offsets (in floats), concatenated in reference return order
constexpr size_t O0 = 0;          // output            (4096,32)
constexpr size_t O1 = 131072;     // features          (73728,128)
constexpr size_t O2 = 9568256;    // pseudo_scores     (73728,32)
constexpr size_t O3 = 11927552;   // partial_target    (73728,32)
constexpr size_t O4 = 14286848;   // score_prot        (4096,32)
constexpr size_t O5 = 14417920;   // new_protos        (32,128)
constexpr size_t O6 = 14422016;   // new_queue         (65536,128)
constexpr size_t O7 = 22810624;   // new_queue_pseudo  (65536,32)
constexpr size_t O8 = 24907776;   // new_queue_partial (65536,32)

__device__ __forceinline__ unsigned short f2b(float x) {
  union { float f; uint32_t u; } v; v.f = x;
  uint32_t u = v.u;
  uint32_t r = (u + 0x7fffu + ((u >> 16) & 1u)) >> 16;   // RNE f32->bf16
  return (unsigned short)r;
}

// ---------------------------------------------------------------------------
// prep_zero: merged weight transposes (3) + zero the atomic accumulators.
//  bid [0,128)   : W_proj_q^T -> wt_pq (bf16 [128][1024])
//  bid [128,160) : W_cls_q^T  -> wt_cls (bf16 [32][1024])
//  bid [160,288) : (0.999*W_proj_k + 0.001*W_proj_q)^T -> wt_pk
//  bid [288,544) : zero CQ|CL|CK (contiguous 4.72 MB)
// block = 256.
// ---------------------------------------------------------------------------
__global__ __launch_bounds__(256) void prep_zero(
    const float* __restrict__ Wpq, const float* __restrict__ Wcq,
    const float* __restrict__ Wpk,
    unsigned short* __restrict__ wt_pq, unsigned short* __restrict__ wt_cls,
    unsigned short* __restrict__ wt_pk, float* __restrict__ zbase) {
  const int bid = blockIdx.x;
  const int t = threadIdx.x;
  if (bid >= 288) {  // zero path
    constexpr int ZN4 = 4096 * (128 + 32 + 128) / 4;  // 294912 float4
    float4* z = (float4*)zbase;
    const float4 zero = {0.f, 0.f, 0.f, 0.f};
    for (int i = (bid - 288) * 256 + t; i < ZN4; i += 256 * 256) z[i] = zero;
    return;
  }
  const float *W1, *W2 = nullptr;
  float a1 = 1.f, a2 = 0.f;
  unsigned short* dst;
  int kb, nb, N;
  if (bid < 128) {
    W1 = Wpq; N = 128; kb = (bid & 31) * 32; nb = (bid >> 5) * 32; dst = wt_pq;
  } else if (bid < 160) {
    W1 = Wcq; N = 32; kb = (bid - 128) * 32; nb = 0; dst = wt_cls;
  } else {
    W1 = Wpk; W2 = Wpq; a1 = 0.999f; a2 = 0.001f; N = 128;
    const int b = bid - 160; kb = (b & 31) * 32; nb = (b >> 5) * 32; dst = wt_pk;
  }
  __shared__ float tile[32][33];
  const int tx = t & 31, ty = t >> 5;
#pragma unroll
  for (int j = 0; j < 4; ++j) {
    const int k = kb + ty + 8 * j;
    float v = W1[(size_t)k * N + nb + tx] * a1;
    if (W2) v += W2[(size_t)k * N + nb + tx] * a2;
    tile[ty + 8 * j][tx] = v;
  }
  __syncthreads();
#pragma unroll
  for (int j = 0; j < 4; ++j) {
    const int n = nb + ty + 8 * j;
    dst[(size_t)n * 1024 + kb + tx] = f2b(tile[tx][ty + 8 * j]);
  }
}

// ---------------------------------------------------------------------------
// gemm_all: all three GEMMs, split-K=2, atomic f32 accumulate.
//  bid [0,512)     : CQ += img_q @ wt_pq^T   (BM=16, BN=128) ks = bid>>8
//  bid [512,1024)  : CK += im_k  @ wt_pk^T   (BM=16, BN=128)
//  bid [1024,1152) : CL += img_q @ wt_cls^T  (BM=64, BN=32)
// block = 256 (4 waves). mfma_f32_16x16x32_bf16, XOR-swizzled LDS,
// register prefetch of the next K-tile issued before each MFMA phase.
// ---------------------------------------------------------------------------
__global__ __launch_bounds__(256) void gemm_all(
    const float* __restrict__ img_q, const float* __restrict__ im_k,
    const unsigned short* __restrict__ wt_pq,
    const unsigned short* __restrict__ wt_pk,
    const unsigned short* __restrict__ wt_cls,
    float* __restrict__ CQ, float* __restrict__ CK, float* __restrict__ CL) {
  __shared__ __align__(16) unsigned char lds[18432];
  const int bid = blockIdx.x;
  const int t = threadIdx.x;
  const int w = t >> 6, l = t & 63;
  const int ar = l & 15, kg = l >> 4;

  if (bid < 1024) {  // ---- type A: BM=16, BN=128 ----
    const bool isq = bid < 512;
    const int b = bid & 511;
    const int m0 = (b & 255) * 16;
    const int kb = (b >> 8) * 512;
    const float* A = isq ? img_q : im_k;
    const unsigned short* Wt = isq ? wt_pq : wt_pk;
    float* C = isq ? CQ : CK;
    unsigned char* sA = lds;          // 16 rows x 128B = 2 KB
    unsigned char* sB = lds + 2048;   // 128 rows x 128B = 16 KB
    const int arow = t >> 4, acol = t & 15;   // A staging: 1 float4/thread
    f32x4 acc0 = {0.f, 0.f, 0.f, 0.f}, acc1 = {0.f, 0.f, 0.f, 0.f};
    float4 av; uint4 bv[4];
    av = *(const float4*)(A + (size_t)(m0 + arow) * 1024 + kb + acol * 4);
#pragma unroll
    for (int i = 0; i < 4; ++i) {
      const int cid = t + i * 256, r = cid >> 3, c = cid & 7;
      bv[i] = *(const uint4*)(Wt + (size_t)r * 1024 + kb + c * 8);
    }
    for (int it = 0; it < 8; ++it) {
      {
        uint2 pk;
        pk.x = (uint32_t)f2b(av.x) | ((uint32_t)f2b(av.y) << 16);
        pk.y = (uint32_t)f2b(av.z) | ((uint32_t)f2b(av.w) << 16);
        *(uint2*)(sA + ((arow * 128 + acol * 8) ^ ((arow & 7) << 4))) = pk;
      }
#pragma unroll
      for (int i = 0; i < 4; ++i) {
        const int cid = t + i * 256, r = cid >> 3, c = cid & 7;
        *(uint4*)(sB + ((r * 128 + c * 16) ^ ((r & 7) << 4))) = bv[i];
      }
      if (it < 7) {  // prefetch next tile; latency hides under MFMA+barriers
        const int k0 = kb + (it + 1) * 64;
        av = *(const float4*)(A + (size_t)(m0 + arow) * 1024 + k0 + acol * 4);
#pragma unroll
        for (int i = 0; i < 4; ++i) {
          const int cid = t + i * 256, r = cid >> 3, c = cid & 7;
          bv[i] = *(const uint4*)(Wt + (size_t)r * 1024 + k0 + c * 8);
        }
      }
      __syncthreads();
      const int cs = w * 32;
#pragma unroll
      for (int s = 0; s < 2; ++s) {
        const int ch = (s * 4 + kg) * 16;
        bf16x8 a = *(const bf16x8*)(sA + ((ar * 128 + ch) ^ ((ar & 7) << 4)));
        const int r0 = cs + ar, r1 = cs + 16 + ar;
        bf16x8 b0 = *(const bf16x8*)(sB + ((r0 * 128 + ch) ^ ((r0 & 7) << 4)));
        bf16x8 b1 = *(const bf16x8*)(sB + ((r1 * 128 + ch) ^ ((r1 & 7) << 4)));
        acc0 = __builtin_amdgcn_mfma_f32_16x16x32_bf16(a, b0, acc0, 0, 0, 0);
        acc1 = __builtin_amdgcn_mfma_f32_16x16x32_bf16(a, b1, acc1, 0, 0, 0);
      }
      __syncthreads();
    }
    const int cs = w * 32;
#pragma unroll
    for (int j = 0; j < 4; ++j) {
      const int row = m0 + kg * 4 + j;
      unsafeAtomicAdd(&C[(size_t)row * 128 + cs + ar], acc0[j]);
      unsafeAtomicAdd(&C[(size_t)row * 128 + cs + 16 + ar], acc1[j]);
    }
  } else {  // ---- type B: cls GEMM, BM=64, BN=32 ----
    const int b2 = bid - 1024;
    const int m0 = (b2 & 63) * 64;
    const int kb = (b2 >> 6) * 512;
    unsigned char* sA = lds;          // 64 rows x 128B = 8 KB
    unsigned char* sB = lds + 8192;   // 32 rows x 128B = 4 KB
    f32x4 acc0 = {0.f, 0.f, 0.f, 0.f}, acc1 = {0.f, 0.f, 0.f, 0.f};
    float4 av[4]; uint4 bv;
#pragma unroll
    for (int i = 0; i < 4; ++i) {
      const int cid = t + i * 256, r = cid >> 4, c = cid & 15;
      av[i] = *(const float4*)(img_q + (size_t)(m0 + r) * 1024 + kb + c * 4);
    }
    { const int r = t >> 3, c = t & 7;
      bv = *(const uint4*)(wt_cls + (size_t)r * 1024 + kb + c * 8); }
    for (int it = 0; it < 8; ++it) {
#pragma unroll
      for (int i = 0; i < 4; ++i) {
        const int cid = t + i * 256, r = cid >> 4, c8 = (cid & 15) * 8;
        uint2 pk;
        pk.x = (uint32_t)f2b(av[i].x) | ((uint32_t)f2b(av[i].y) << 16);
        pk.y = (uint32_t)f2b(av[i].z) | ((uint32_t)f2b(av[i].w) << 16);
        *(uint2*)(sA + ((r * 128 + c8) ^ ((r & 7) << 4))) = pk;
      }
      { const int r = t >> 3, c = t & 7;
        *(uint4*)(sB + ((r * 128 + c * 16) ^ ((r & 7) << 4))) = bv; }
      if (it < 7) {
        const int k0 = kb + (it + 1) * 64;
#pragma unroll
        for (int i = 0; i < 4; ++i) {
          const int cid = t + i * 256, r = cid >> 4, c = cid & 15;
          av[i] = *(const float4*)(img_q + (size_t)(m0 + r) * 1024 + k0 + c * 4);
        }
        const int r = t >> 3, c = t & 7;
        bv = *(const uint4*)(wt_cls + (size_t)r * 1024 + k0 + c * 8);
      }
      __syncthreads();
#pragma unroll
      for (int s = 0; s < 2; ++s) {
        const int ch = (s * 4 + kg) * 16;
        const int ra = w * 16 + ar;
        bf16x8 a = *(const bf16x8*)(sA + ((ra * 128 + ch) ^ ((ra & 7) << 4)));
        bf16x8 b0 = *(const bf16x8*)(sB + ((ar * 128 + ch) ^ ((ar & 7) << 4)));
        bf16x8 b1 = *(const bf16x8*)(sB + (((16 + ar) * 128 + ch) ^ ((ar & 7) << 4)));
        acc0 = __builtin_amdgcn_mfma_f32_16x16x32_bf16(a, b0, acc0, 0, 0, 0);
        acc1 = __builtin_amdgcn_mfma_f32_16x16x32_bf16(a, b1, acc1, 0, 0, 0);
      }
      __syncthreads();
    }
#pragma unroll
    for (int j = 0; j < 4; ++j) {
      const int row = m0 + w * 16 + kg * 4 + j;
      unsafeAtomicAdd(&CL[(size_t)row * 32 + ar], acc0[j]);
      unsafeAtomicAdd(&CL[(size_t)row * 32 + 16 + ar], acc1[j]);
    }
  }
}

// ---------------------------------------------------------------------------
// post_all: q epilogue (1024 blocks) + k epilogue (1024) + queue copies (3072).
// block = 256.
// ---------------------------------------------------------------------------
__global__ __launch_bounds__(256) void post_all(
    const float* __restrict__ CQ, const float* __restrict__ CL,
    const float* __restrict__ CK, const float* __restrict__ bias,
    const float* __restrict__ partialY, const float* __restrict__ protos,
    const float* __restrict__ queue, const float* __restrict__ qp,
    const float* __restrict__ qpt, float* __restrict__ out,
    int* __restrict__ labels) {
  __shared__ float pr[32 * 129];
  __shared__ float qs[4][128];
  const int bid = blockIdx.x;
  const int t = threadIdx.x;
  const int w = t >> 6, l = t & 63;

  if (bid < 1024) {  // ---- q-path ----
    for (int i = t; i < 4096; i += 256) pr[(i >> 7) * 129 + (i & 127)] = protos[i];
    __syncthreads();
    const int row = bid * 4 + w;
    // logits + bias, softmax, * partial_Y
    float logit = -1e30f;
    if (l < 32) logit = CL[(size_t)row * 32 + l] + bias[l];
    float m = logit;
    for (int o = 32; o; o >>= 1) m = fmaxf(m, __shfl_xor(m, o));
    const float e = (l < 32) ? __expf(logit - m) : 0.f;
    float ssum = e;
    for (int o = 32; o; o >>= 1) ssum += __shfl_xor(ssum, o);
    const float py = (l < 32) ? partialY[(size_t)row * 32 + l] : 0.f;
    const float p = e / ssum * py;
    if (l < 32) {
      out[O0 + (size_t)row * 32 + l] = logit;
      out[O2 + (size_t)row * 32 + l] = p;
      out[O2 + (size_t)(4096 + row) * 32 + l] = p;
      out[O7 + (size_t)row * 32 + l] = p;
      out[O3 + (size_t)row * 32 + l] = py;
      out[O3 + (size_t)(4096 + row) * 32 + l] = py;
      out[O8 + (size_t)row * 32 + l] = py;
    }
    // argmax (first-index-wins on ties)
    float av = (l < 32) ? p : -1.f;
    int ai = (l < 32) ? l : 1000;
    for (int o = 32; o; o >>= 1) {
      const float ov = __shfl_xor(av, o);
      const int oi = __shfl_xor(ai, o);
      if (ov > av || (ov == av && oi < ai)) { av = ov; ai = oi; }
    }
    if (l == 0) labels[row] = ai;
    // l2norm(q)
    float v0 = CQ[(size_t)row * 128 + l], v1 = CQ[(size_t)row * 128 + 64 + l];
    float ss = v0 * v0 + v1 * v1;
    for (int o = 32; o; o >>= 1) ss += __shfl_xor(ss, o);
    const float den = fmaxf(sqrtf(ss), 1e-12f);
    v0 /= den; v1 /= den;
    out[O1 + (size_t)row * 128 + l] = v0;
    out[O1 + (size_t)row * 128 + 64 + l] = v1;
    qs[w][l] = v0;
    qs[w][64 + l] = v1;  // same-wave LDS, lockstep
    // score_prot
    const int c = l & 31;
    const int dh = (l >> 5) * 64;
    float acc = 0.f;
#pragma unroll
    for (int d = 0; d < 64; ++d) acc += qs[w][dh + d] * pr[c * 129 + dh + d];
    acc += __shfl_xor(acc, 32);
    float sm = acc;
    for (int o = 16; o; o >>= 1) sm = fmaxf(sm, __shfl_xor(sm, o));
    const float ee = __expf(acc - sm);
    float s2 = ee;
    for (int o = 16; o; o >>= 1) s2 += __shfl_xor(s2, o);
    if (l < 32) out[O4 + (size_t)row * 32 + l] = ee / s2;
  } else if (bid < 2048) {  // ---- k-path ----
    const int row = (bid - 1024) * 4 + w;
    const float* ck = CK + (size_t)row * 128;
    float v0 = ck[l], v1 = ck[64 + l];
    float ss = v0 * v0 + v1 * v1;
    for (int o = 32; o; o >>= 1) ss += __shfl_xor(ss, o);
    const float den = fmaxf(sqrtf(ss), 1e-12f);
    v0 /= den; v1 /= den;
    out[O1 + (size_t)(4096 + row) * 128 + l] = v0;
    out[O1 + (size_t)(4096 + row) * 128 + 64 + l] = v1;
    out[O6 + (size_t)row * 128 + l] = v0;
    out[O6 + (size_t)row * 128 + 64 + l] = v1;
  } else {  // ---- copy path ----
    constexpr long NQ4 = (long)65536 * 128 / 4;
    constexpr long NP4 = (long)65536 * 32 / 4;
    constexpr long TOT = NQ4 + 2 * NP4;
    float4* o4 = (float4*)out;
    for (long idx = (long)(bid - 2048) * 256 + t; idx < TOT; idx += 3072L * 256) {
      if (idx < NQ4) {
        const float4 v = ((const float4*)queue)[idx];
        o4[O1 / 4 + (2L * 4096 * 128) / 4 + idx] = v;
        if ((idx >> 5) >= 4096) o4[O6 / 4 + idx] = v;
      } else if (idx < NQ4 + NP4) {
        const long i = idx - NQ4;
        const float4 v = ((const float4*)qp)[i];
        o4[O2 / 4 + (2L * 4096 * 32) / 4 + i] = v;
        if ((i >> 3) >= 4096) o4[O7 / 4 + i] = v;
      } else {
        const long i = idx - NQ4 - NP4;
        const float4 v = ((const float4*)qpt)[i];
        o4[O3 / 4 + (2L * 4096 * 32) / 4 + i] = v;
        if ((i >> 3) >= 4096) o4[O8 / 4 + i] = v;
      }
    }
  }
}

// ---------------------------------------------------------------------------
// proto_up: per-class EMA scan as weighted sum; shfl parallel scan; 4-way ILP.
// grid 32, block 128.
// ---------------------------------------------------------------------------
__global__ __launch_bounds__(128) void proto_up(const int* __restrict__ labels,
                                                const float* __restrict__ qfeat,
                                                const float* __restrict__ protos,
                                                float* __restrict__ out) {
  __shared__ int lab[4096];   // reused as float weights after list build
  __shared__ int list[4096];
  __shared__ int cnt[128];
  __shared__ float red[2];
  const int c = blockIdx.x, t = threadIdx.x;
  for (int i = t; i < 4096; i += 128) lab[i] = labels[i];
  __syncthreads();
  int cn = 0;
#pragma unroll
  for (int j = 0; j < 32; ++j) {
    const int jj = (j + t) & 31;
    cn += (lab[t * 32 + jj] == c) ? 1 : 0;
  }
  // per-wave inclusive scan, then wave1 adds wave0 total
  int inc = cn;
  const int l = t & 63;
  for (int o = 1; o < 64; o <<= 1) {
    const int n = __shfl_up(inc, o);
    if (l >= o) inc += n;
  }
  cnt[t] = inc;
  __syncthreads();
  const int w0tot = cnt[63];
  const int k = cnt[127] + w0tot;
  int off = inc - cn + ((t >= 64) ? w0tot : 0);
  for (int j = 0; j < 32; ++j) {  // in-order append (order matters)
    const int i = t * 32 + j;
    if (lab[i] == c) list[off++] = i;
  }
  __syncthreads();
  float* wf = (float*)lab;  // lab dead from here on
  for (int j = t; j < k; j += 128)
    wf[j] = 0.01f * __powf(0.99f, (float)(k - 1 - j));
  __syncthreads();
  float a0 = protos[(size_t)c * 128 + t] * __powf(0.99f, (float)k);
  float a1 = 0.f, a2 = 0.f, a3 = 0.f;
  int j = 0;
  for (; j + 4 <= k; j += 4) {  // 4 independent chains -> loads pipeline
    a0 += wf[j]     * qfeat[(size_t)list[j] * 128 + t];
    a1 += wf[j + 1] * qfeat[(size_t)list[j + 1] * 128 + t];
    a2 += wf[j + 2] * qfeat[(size_t)list[j + 2] * 128 + t];
    a3 += wf[j + 3] * qfeat[(size_t)list[j + 3] * 128 + t];
  }
  for (; j < k; ++j) a0 += wf[j] * qfeat[(size_t)list[j] * 128 + t];
  const float acc = (a0 + a1) + (a2 + a3);
  float ss = acc * acc;
  for (int o = 32; o; o >>= 1) ss += __shfl_xor(ss, o);
  if ((t & 63) == 0) red[t >> 6] = ss;
  __syncthreads();
  const float tot = red[0] + red[1];
  out[O5 + (size_t)c * 128 + t] = acc / fmaxf(sqrtf(tot), 1e-12f);
}

// ---------------------------------------------------------------------------
extern "C" void kernel_launch(void* const* d_in, const int* in_sizes, int n_in,
                              void* d_out, int out_size, void* d_ws, size_t ws_size,
                              hipStream_t stream) {
  const float* img_q    = (const float*)d_in[0];
  const float* im_k     = (const float*)d_in[1];
  const float* partialY = (const float*)d_in[2];
  // d_in[3]=W_cls_q used below; d_in[6]=W_cls_k, d_in[7]=b_cls_k dead
  const float* W_cls_q  = (const float*)d_in[3];
  const float* b_cls_q  = (const float*)d_in[4];
  const float* W_proj_q = (const float*)d_in[5];
  const float* W_proj_k = (const float*)d_in[8];
  const float* protos   = (const float*)d_in[9];
  const float* queue    = (const float*)d_in[10];
  const float* queue_ps = (const float*)d_in[11];
  const float* queue_pt = (const float*)d_in[12];
  float* out = (float*)d_out;

  // workspace layout (~5.1 MB)
  unsigned short* wt_pq  = (unsigned short*)d_ws;       // bf16 [128][1024]
  unsigned short* wt_cls = wt_pq + 128 * 1024;          // bf16 [32][1024]
  unsigned short* wt_pk  = wt_cls + 32 * 1024;          // bf16 [128][1024]
  float* CQ = (float*)(wt_pk + 128 * 1024);             // f32 [4096][128]
  float* CL = CQ + (size_t)4096 * 128;                  // f32 [4096][32]
  float* CK = CL + (size_t)4096 * 32;                   // f32 [4096][128]
  int* labels = (int*)(CK + (size_t)4096 * 128);        // int [4096]

  prep_zero<<<544, 256, 0, stream>>>(W_proj_q, W_cls_q, W_proj_k,
                                     wt_pq, wt_cls, wt_pk, CQ);
  gemm_all<<<1152, 256, 0, stream>>>(img_q, im_k, wt_pq, wt_pk, wt_cls,
                                     CQ, CK, CL);
  post_all<<<5120, 256, 0, stream>>>(CQ, CL, CK, b_cls_q, partialY, protos,
                                     queue, queue_ps, queue_pt, out, labels);
  proto_up<<<32, 128, 0, stream>>>(labels, out + O1, protos, out);
}